// Round 18
// baseline (663.286 us; speedup 1.0000x reference)
//
#include <hip/hip_runtime.h>
#include <hip/hip_bf16.h>

// RGBuvHistBlock: x (8,3,65536) f32 -> normalized uv histograms (8,3,64,64) f32.
// hist[b,c,h,g] = sum_p (Iy*ku[h]) * kv[g]  == Wu^T (64xN) * Kv (Nx64) GEMM.
// r11 main loop (verified, 105.9us); ONLY the epilogue changed:
//   priv mode (ws large enough): each block plain-stores its 16KB histogram to a
//     private slot -> ZERO global atomics; norm_kernel reduces the 32 slots/bc.
//   fallback mode: 8-copy atomicAdd flush (contention 32-way -> 4-way).

typedef __bf16 bf16x8 __attribute__((ext_vector_type(8)));
typedef float  f32x4  __attribute__((ext_vector_type(4)));

constexpr int   HBINS = 64;
constexpr int   HB2   = HBINS * HBINS;       // 4096
constexpr float EPSF  = 1e-6f;
constexpr int   BATCH = 8;
constexpr int   NPIX  = 65536;
constexpr int   NBC   = 24;                  // 8 batches * 3 channels
constexpr int   NCOPY = 8;                   // fallback: histogram copies per bc
constexpr int   CHUNKS = 32;                 // 768 blocks (verified grid)
constexpr int   PPC   = NPIX / CHUNKS;       // 2048 pixels per block
constexpr int   ROUNDS = PPC / 256;          // 8 staging rounds per block
constexpr float BINSTEP  = 300.0f / 63.0f;   // lin[i]/sigma step
constexpr float LOGSCALE = 34.6573590279973f; // 50 * ln(2): log2-diff -> (ln-diff)/sigma

__global__ __launch_bounds__(256, 3) void hist_kernel(const float* __restrict__ x,
                                                      float* __restrict__ ws,
                                                      int priv) {
    const int bc   = blockIdx.y;             // 0..23
    const int b    = bc / 3;
    const int c    = bc - b * 3;
    const int t    = threadIdx.x;
    const int lane = t & 63;
    const int w    = t >> 6;                 // wave 0..3
    const int kgrp = lane >> 4;              // 0..3
    const int l16  = lane & 15;

    __shared__ float cu_s[2][256];
    __shared__ float cv_s[2][256];
    __shared__ float iy_s[2][256];
    __shared__ float lhist[HB2];             // 16 KB block-level accumulator

    for (int i = t; i < HB2; i += 256) lhist[i] = 0.0f;
    // fenced by the prologue __syncthreads below.

    f32x4 acc[4][4];
#pragma unroll
    for (int m = 0; m < 4; ++m)
#pragma unroll
        for (int n = 0; n < 4; ++n) acc[m][n] = (f32x4){0.f, 0.f, 0.f, 0.f};

    const float* xr = x + ((size_t)b * 3 + 0) * NPIX;
    const float* xg = x + ((size_t)b * 3 + 1) * NPIX;
    const float* xb = x + ((size_t)b * 3 + 2) * NPIX;
    const int pix0 = blockIdx.x * PPC;

    // producer math: rgb -> (cu, cv, iy)
    auto produce = [&](float r, float g, float bl, float& cu, float& cv, float& iy) {
        r  = fminf(fmaxf(fmaf(r,  0.5f, 0.5f), 0.0f), 1.0f);
        g  = fminf(fmaxf(fmaf(g,  0.5f, 0.5f), 0.0f), 1.0f);
        bl = fminf(fmaxf(fmaf(bl, 0.5f, 0.5f), 0.0f), 1.0f);
        const float l2r = __log2f(r  + EPSF);
        const float l2g = __log2f(g  + EPSF);
        const float l2b = __log2f(bl + EPSF);
        float lc, lu, lv;
        if (c == 0)      { lc = l2r; lu = l2g; lv = l2b; }  // u=r-g, v=r-b
        else if (c == 1) { lc = l2g; lu = l2r; lv = l2b; }  // u=g-r, v=g-b
        else             { lc = l2b; lu = l2r; lv = l2g; }  // u=b-r, v=b-g
        cu = (lc - lu) * LOGSCALE;
        cv = (lc - lv) * LOGSCALE;
        iy = __builtin_amdgcn_sqrtf(fmaf(r, r, fmaf(g, g, fmaf(bl, bl, EPSF))));
    };

    // ---- prologue: stage round 0 ----
    {
        float cu, cv, iy;
        produce(xr[pix0 + t], xg[pix0 + t], xb[pix0 + t], cu, cv, iy);
        cu_s[0][t] = cu; cv_s[0][t] = cv; iy_s[0][t] = iy;
    }
    __syncthreads();

    for (int rnd = 0; rnd < ROUNDS; ++rnd) {
        const int cur = rnd & 1;
        const int nxt = cur ^ 1;
        const bool have_next = (rnd + 1 < ROUNDS);

        // ---- issue next round's loads BEFORE the bulk compute ----
        float rn = 0.f, gn = 0.f, bn = 0.f;
        if (have_next) {
            const int p = pix0 + (rnd + 1) * 256 + t;
            rn = xr[p]; gn = xg[p]; bn = xb[p];
        }

        // ---- consume buf[cur]: wave w owns pixels [w*64, w*64+64) ----
#pragma unroll
        for (int ks = 0; ks < 2; ++ks) {
            const int k0 = w * 64 + ks * 32 + kgrp * 8;   // 8-aligned
            float cu8[8], cv8[8], iy8[8];
            *(float4*)&cu8[0] = *(const float4*)&cu_s[cur][k0];
            *(float4*)&cu8[4] = *(const float4*)&cu_s[cur][k0 + 4];
            *(float4*)&cv8[0] = *(const float4*)&cv_s[cur][k0];
            *(float4*)&cv8[4] = *(const float4*)&cv_s[cur][k0 + 4];
            *(float4*)&iy8[0] = *(const float4*)&iy_s[cur][k0];
            *(float4*)&iy8[4] = *(const float4*)&iy_s[cur][k0 + 4];

            // B fragments: kv at bins g = n*16 + l16 (no Iy scale)
            bf16x8 bfr[4];
#pragma unroll
            for (int n = 0; n < 4; ++n) {
                const float ling = (float)(n * 16 + l16) * BINSTEP - 150.0f;
#pragma unroll
                for (int j = 0; j < 8; ++j) {
                    const float d = cv8[j] - ling;
                    bfr[n][j] = (__bf16)__builtin_amdgcn_rcpf(fmaf(d, d, 1.0f));
                }
            }
            // A fragments: wu = Iy*ku at bins h = m*16 + l16, then 4 MFMAs each
#pragma unroll
            for (int m = 0; m < 4; ++m) {
                const float linh = (float)(m * 16 + l16) * BINSTEP - 150.0f;
                bf16x8 af;
#pragma unroll
                for (int j = 0; j < 8; ++j) {
                    const float d = cu8[j] - linh;
                    af[j] = (__bf16)(iy8[j] * __builtin_amdgcn_rcpf(fmaf(d, d, 1.0f)));
                }
#pragma unroll
                for (int n = 0; n < 4; ++n)
                    acc[m][n] = __builtin_amdgcn_mfma_f32_16x16x32_bf16(af, bfr[n], acc[m][n], 0, 0, 0);
            }
        }

        // ---- producer math + write for round rnd+1 (loads long in flight) ----
        if (have_next) {
            float cu, cv, iy;
            produce(rn, gn, bn, cu, cv, iy);
            cu_s[nxt][t] = cu; cv_s[nxt][t] = cv; iy_s[nxt][t] = iy;
        }
        __syncthreads();   // one barrier per round
    }

    // ---- block reduction: 4 waves -> lhist ----
    const int crow = kgrp * 4;   // C/D: col = lane&15, row = (lane>>4)*4 + ri  [m89]
#pragma unroll
    for (int m = 0; m < 4; ++m)
#pragma unroll
        for (int n = 0; n < 4; ++n)
#pragma unroll
            for (int ri = 0; ri < 4; ++ri)
                atomicAdd(&lhist[(m * 16 + crow + ri) * HBINS + n * 16 + l16], acc[m][n][ri]);
    __syncthreads();

    if (priv) {
        // zero-atomic flush: private per-block slot, coalesced float4 stores
        float* gh = ws + ((size_t)bc * CHUNKS + blockIdx.x) * HB2;
        for (int i = t * 4; i < HB2; i += 1024)
            *(float4*)&gh[i] = *(const float4*)&lhist[i];
    } else {
        // fallback: 8-copy atomic flush (contention 32-way -> 4-way)
        float* gh = ws + ((size_t)bc * NCOPY + (blockIdx.x & (NCOPY - 1))) * HB2;
        for (int i = t; i < HB2; i += 256) atomicAdd(&gh[i], lhist[i]);
    }
}

__global__ __launch_bounds__(256) void norm_kernel(const float* __restrict__ ws,
                                                   float* __restrict__ out,
                                                   int ncopy) {
    const int b = blockIdx.x;
    const float* h = ws  + (size_t)b * 3 * ncopy * HB2;
    float*       o = out + (size_t)b * 3 * HB2;
    const int t = threadIdx.x;
    const int n = 3 * HB2;   // 12288 output bins per batch

    // total over all channels and copies
    float s = 0.0f;
    for (int i = t; i < 3 * ncopy * HB2; i += 256) s += h[i];
#pragma unroll
    for (int off = 32; off > 0; off >>= 1) s += __shfl_down(s, off, 64);

    __shared__ float partial[4];
    if ((t & 63) == 0) partial[t >> 6] = s;
    __syncthreads();
    const float total = partial[0] + partial[1] + partial[2] + partial[3];
    const float inv = 1.0f / (total + EPSF);

    for (int i = t; i < n; i += 256) {
        const int c  = i >> 12;              // /4096
        const int hg = i & 4095;
        float v = 0.0f;
        for (int k = 0; k < ncopy; ++k)
            v += h[((size_t)c * ncopy + k) * HB2 + hg];
        o[i] = v * inv;
    }
}

extern "C" void kernel_launch(void* const* d_in, const int* in_sizes, int n_in,
                              void* d_out, int out_size, void* d_ws, size_t ws_size,
                              hipStream_t stream) {
    const float* x   = (const float*)d_in[0];
    float*       out = (float*)d_out;
    float*       ws  = (float*)d_ws;

    const size_t priv_bytes = (size_t)NBC * CHUNKS * HB2 * sizeof(float);  // 12.6 MB
    const bool   priv       = ws_size >= priv_bytes;   // constant across calls

    if (!priv) {
        // fallback path needs zeroed accumulator copies
        hipMemsetAsync(ws, 0, (size_t)NBC * NCOPY * HB2 * sizeof(float), stream);
    }

    dim3 grid(CHUNKS, NBC);
    hist_kernel<<<grid, 256, 0, stream>>>(x, ws, priv ? 1 : 0);
    norm_kernel<<<BATCH, 256, 0, stream>>>(ws, out, priv ? CHUNKS : NCOPY);
}

// Round 19
// 159.442 us; speedup vs baseline: 4.1600x; 4.1600x over previous
//
#include <hip/hip_runtime.h>
#include <hip/hip_bf16.h>

// RGBuvHistBlock: x (8,3,65536) f32 -> normalized uv histograms (8,3,64,64) f32.
// hist[b,c,h,g] = sum_p (Iy*ku[h]) * kv[g]  == Wu^T (64xN) * Kv (Nx64) GEMM.
// r11 main loop (verified 105.9us) + 8-copy atomic flush (contention 32->4-way).
// Epilogue reduction now PARALLEL with compile-time bounds (r18 lesson: runtime
// ncopy + 8-block norm = 507us latency disaster).
// ws layout: [NBC*NCOPY*HB2 floats hist copies][BATCH floats totals]  ~3.15 MB

typedef __bf16 bf16x8 __attribute__((ext_vector_type(8)));
typedef float  f32x4  __attribute__((ext_vector_type(4)));

constexpr int   HBINS = 64;
constexpr int   HB2   = HBINS * HBINS;       // 4096
constexpr float EPSF  = 1e-6f;
constexpr int   BATCH = 8;
constexpr int   NPIX  = 65536;
constexpr int   NBC   = 24;                  // 8 batches * 3 channels
constexpr int   NCOPY = 8;                   // histogram copies per bc (compile-time!)
constexpr int   CHUNKS = 32;                 // 768 blocks (verified grid)
constexpr int   PPC   = NPIX / CHUNKS;       // 2048 pixels per block
constexpr int   ROUNDS = PPC / 256;          // 8 staging rounds per block
constexpr int   SEGS  = 4;                   // reduce: segments per bc
constexpr float BINSTEP  = 300.0f / 63.0f;   // lin[i]/sigma step
constexpr float LOGSCALE = 34.6573590279973f; // 50 * ln(2): log2-diff -> (ln-diff)/sigma

__global__ __launch_bounds__(256, 3) void hist_kernel(const float* __restrict__ x,
                                                      float* __restrict__ ws) {
    const int bc   = blockIdx.y;             // 0..23
    const int b    = bc / 3;
    const int c    = bc - b * 3;
    const int t    = threadIdx.x;
    const int lane = t & 63;
    const int w    = t >> 6;                 // wave 0..3
    const int kgrp = lane >> 4;              // 0..3
    const int l16  = lane & 15;

    __shared__ float cu_s[2][256];
    __shared__ float cv_s[2][256];
    __shared__ float iy_s[2][256];
    __shared__ float lhist[HB2];             // 16 KB block-level accumulator

    for (int i = t; i < HB2; i += 256) lhist[i] = 0.0f;
    // fenced by the prologue __syncthreads below.

    f32x4 acc[4][4];
#pragma unroll
    for (int m = 0; m < 4; ++m)
#pragma unroll
        for (int n = 0; n < 4; ++n) acc[m][n] = (f32x4){0.f, 0.f, 0.f, 0.f};

    const float* xr = x + ((size_t)b * 3 + 0) * NPIX;
    const float* xg = x + ((size_t)b * 3 + 1) * NPIX;
    const float* xb = x + ((size_t)b * 3 + 2) * NPIX;
    const int pix0 = blockIdx.x * PPC;

    // producer math: rgb -> (cu, cv, iy)
    auto produce = [&](float r, float g, float bl, float& cu, float& cv, float& iy) {
        r  = fminf(fmaxf(fmaf(r,  0.5f, 0.5f), 0.0f), 1.0f);
        g  = fminf(fmaxf(fmaf(g,  0.5f, 0.5f), 0.0f), 1.0f);
        bl = fminf(fmaxf(fmaf(bl, 0.5f, 0.5f), 0.0f), 1.0f);
        const float l2r = __log2f(r  + EPSF);
        const float l2g = __log2f(g  + EPSF);
        const float l2b = __log2f(bl + EPSF);
        float lc, lu, lv;
        if (c == 0)      { lc = l2r; lu = l2g; lv = l2b; }  // u=r-g, v=r-b
        else if (c == 1) { lc = l2g; lu = l2r; lv = l2b; }  // u=g-r, v=g-b
        else             { lc = l2b; lu = l2r; lv = l2g; }  // u=b-r, v=b-g
        cu = (lc - lu) * LOGSCALE;
        cv = (lc - lv) * LOGSCALE;
        iy = __builtin_amdgcn_sqrtf(fmaf(r, r, fmaf(g, g, fmaf(bl, bl, EPSF))));
    };

    // ---- prologue: stage round 0 ----
    {
        float cu, cv, iy;
        produce(xr[pix0 + t], xg[pix0 + t], xb[pix0 + t], cu, cv, iy);
        cu_s[0][t] = cu; cv_s[0][t] = cv; iy_s[0][t] = iy;
    }
    __syncthreads();

    for (int rnd = 0; rnd < ROUNDS; ++rnd) {
        const int cur = rnd & 1;
        const int nxt = cur ^ 1;
        const bool have_next = (rnd + 1 < ROUNDS);

        // ---- issue next round's loads BEFORE the bulk compute ----
        float rn = 0.f, gn = 0.f, bn = 0.f;
        if (have_next) {
            const int p = pix0 + (rnd + 1) * 256 + t;
            rn = xr[p]; gn = xg[p]; bn = xb[p];
        }

        // ---- consume buf[cur]: wave w owns pixels [w*64, w*64+64) ----
#pragma unroll
        for (int ks = 0; ks < 2; ++ks) {
            const int k0 = w * 64 + ks * 32 + kgrp * 8;   // 8-aligned
            float cu8[8], cv8[8], iy8[8];
            *(float4*)&cu8[0] = *(const float4*)&cu_s[cur][k0];
            *(float4*)&cu8[4] = *(const float4*)&cu_s[cur][k0 + 4];
            *(float4*)&cv8[0] = *(const float4*)&cv_s[cur][k0];
            *(float4*)&cv8[4] = *(const float4*)&cv_s[cur][k0 + 4];
            *(float4*)&iy8[0] = *(const float4*)&iy_s[cur][k0];
            *(float4*)&iy8[4] = *(const float4*)&iy_s[cur][k0 + 4];

            // B fragments: kv at bins g = n*16 + l16 (no Iy scale)
            bf16x8 bfr[4];
#pragma unroll
            for (int n = 0; n < 4; ++n) {
                const float ling = (float)(n * 16 + l16) * BINSTEP - 150.0f;
#pragma unroll
                for (int j = 0; j < 8; ++j) {
                    const float d = cv8[j] - ling;
                    bfr[n][j] = (__bf16)__builtin_amdgcn_rcpf(fmaf(d, d, 1.0f));
                }
            }
            // A fragments: wu = Iy*ku at bins h = m*16 + l16, then 4 MFMAs each
#pragma unroll
            for (int m = 0; m < 4; ++m) {
                const float linh = (float)(m * 16 + l16) * BINSTEP - 150.0f;
                bf16x8 af;
#pragma unroll
                for (int j = 0; j < 8; ++j) {
                    const float d = cu8[j] - linh;
                    af[j] = (__bf16)(iy8[j] * __builtin_amdgcn_rcpf(fmaf(d, d, 1.0f)));
                }
#pragma unroll
                for (int n = 0; n < 4; ++n)
                    acc[m][n] = __builtin_amdgcn_mfma_f32_16x16x32_bf16(af, bfr[n], acc[m][n], 0, 0, 0);
            }
        }

        // ---- producer math + write for round rnd+1 (loads long in flight) ----
        if (have_next) {
            float cu, cv, iy;
            produce(rn, gn, bn, cu, cv, iy);
            cu_s[nxt][t] = cu; cv_s[nxt][t] = cv; iy_s[nxt][t] = iy;
        }
        __syncthreads();   // one barrier per round
    }

    // ---- block reduction: 4 waves -> lhist, then 8-copy atomic flush ----
    const int crow = kgrp * 4;   // C/D: col = lane&15, row = (lane>>4)*4 + ri  [m89]
#pragma unroll
    for (int m = 0; m < 4; ++m)
#pragma unroll
        for (int n = 0; n < 4; ++n)
#pragma unroll
            for (int ri = 0; ri < 4; ++ri)
                atomicAdd(&lhist[(m * 16 + crow + ri) * HBINS + n * 16 + l16], acc[m][n][ri]);
    __syncthreads();

    float* gh = ws + ((size_t)bc * NCOPY + (blockIdx.x & (NCOPY - 1))) * HB2;
    for (int i = t; i < HB2; i += 256) atomicAdd(&gh[i], lhist[i]);
}

// reduce: 96 blocks; block handles 1024 bins of one bc: sum NCOPY copies ->
// unnormalized out; block partial -> atomicAdd to per-batch total.
__global__ __launch_bounds__(256) void reduce_kernel(const float* __restrict__ ws,
                                                     float* __restrict__ out,
                                                     float* __restrict__ totals) {
    const int bc  = blockIdx.x >> 2;         // 0..23
    const int seg = blockIdx.x & 3;          // 0..3
    const int b   = bc / 3;
    const int t   = threadIdx.x;
    const float* h = ws + (size_t)bc * NCOPY * HB2 + seg * 1024;
    float*       o = out + (size_t)bc * HB2 + seg * 1024;

    float psum = 0.0f;
#pragma unroll
    for (int r = 0; r < 4; ++r) {            // 4 bins per thread
        const int i = r * 256 + t;
        float v = 0.0f;
#pragma unroll
        for (int k = 0; k < NCOPY; ++k) v += h[(size_t)k * HB2 + i];
        o[i] = v;
        psum += v;
    }
    // block-reduce psum -> one atomicAdd
#pragma unroll
    for (int off = 32; off > 0; off >>= 1) psum += __shfl_down(psum, off, 64);
    __shared__ float part[4];
    if ((t & 63) == 0) part[t >> 6] = psum;
    __syncthreads();
    if (t == 0)
        atomicAdd(&totals[b], part[0] + part[1] + part[2] + part[3]);
}

// scale: 24 blocks; out[bc] *= 1/(total[b]+eps), in place.
__global__ __launch_bounds__(256) void scale_kernel(float* __restrict__ out,
                                                    const float* __restrict__ totals) {
    const int bc = blockIdx.x;
    const int b  = bc / 3;
    const float inv = 1.0f / (totals[b] + EPSF);
    float* o = out + (size_t)bc * HB2;
    const int t = threadIdx.x;
#pragma unroll
    for (int r = 0; r < 4; ++r) {
        const int i = (r * 256 + t) * 4;
        float4 v = *(const float4*)&o[i];
        v.x *= inv; v.y *= inv; v.z *= inv; v.w *= inv;
        *(float4*)&o[i] = v;
    }
}

extern "C" void kernel_launch(void* const* d_in, const int* in_sizes, int n_in,
                              void* d_out, int out_size, void* d_ws, size_t ws_size,
                              hipStream_t stream) {
    const float* x      = (const float*)d_in[0];
    float*       out    = (float*)d_out;
    float*       ws     = (float*)d_ws;
    float*       totals = ws + (size_t)NBC * NCOPY * HB2;

    // zero hist copies + totals (ws is poisoned each call)
    hipMemsetAsync(ws, 0, ((size_t)NBC * NCOPY * HB2 + BATCH) * sizeof(float), stream);

    dim3 grid(CHUNKS, NBC);
    hist_kernel<<<grid, 256, 0, stream>>>(x, ws);
    reduce_kernel<<<NBC * SEGS, 256, 0, stream>>>(ws, out, totals);
    scale_kernel<<<NBC, 256, 0, stream>>>(out, totals);
}